// Round 20
// baseline (181.217 us; speedup 1.0000x reference)
//
#include <hip/hip_runtime.h>
#include <hip/hip_bf16.h>

#define NCOLS 32768
#define NZ 64
#define NT 40
#define DTF 30.0f
#define GAMMAC 0.55f

typedef _Float16 f16;

// Cap the pre-RA scheduler's prefetch window (r4->r5 lesson).
#define SBAR() __builtin_amdgcn_sched_barrier(0)

// swap lanes (0,1) and (2,3) within each quad: u<->v, t<->s
__device__ __forceinline__ float dpp_swap1(float x) {
    return __int_as_float(__builtin_amdgcn_mov_dpp(__float_as_int(x), 0xB1, 0xF, 0xF, true));
}
__device__ __forceinline__ unsigned int packh2(float a, float b) {
    union { f16 h[2]; unsigned int u; } v;
    v.h[0] = (f16)a; v.h[1] = (f16)b; return v.u;
}
__device__ __forceinline__ unsigned short f16bits(float a) {
    union { f16 h; unsigned short u; } v; v.h = (f16)a; return v.u;
}
__device__ __forceinline__ float lo16f(unsigned int x) {
    union { unsigned int u; f16 h[2]; } v; v.u = x; return (float)v.h[0];
}
__device__ __forceinline__ float hi16f(unsigned int x) {
    union { unsigned int u; f16 h[2]; } v; v.u = x; return (float)v.h[1];
}
__device__ __forceinline__ unsigned selu4(uint4 v, int i) {
    return (i == 0) ? v.x : (i == 1) ? v.y : (i == 2) ? v.z : v.w;
}

// r20 = r13's envelope/thread-map (best: 87us) + IN-THREAD BABE:
// each thread runs TWO independent 32-level Thomas chains (top k=0..31,
// bottom k=63..32, both-ends elimination, r9-proven junction algebra solved
// in-register -- no cross-thread exchange), halving the serial dependency
// depth per step (128 -> 64) that r13's 60%-stall VALU was blocked on.
// r19 lesson: cross-thread BABE pays thread-doubling overhead and loses;
// in-thread BABE keeps r13's thread economy. Same 80KB LDS (proven 128-VGPR
// allocator cap envelope: r2/r3 granted 128 here), same 32 reads/step.
__global__ __launch_bounds__(256, 2) void scm_kernel(
    const float* __restrict__ u0, const float* __restrict__ v0,
    const float* __restrict__ t0, const float* __restrict__ s0,
    const float* __restrict__ hz, const float* __restrict__ akv,
    const float* __restrict__ akt, const float* __restrict__ tfo,
    const float* __restrict__ sfo, const float* __restrict__ uss,
    const float* __restrict__ vss, const float* __restrict__ usb,
    const float* __restrict__ vsb, const float* __restrict__ fcor,
    float* __restrict__ out)
{
    __shared__ uint4 Wsh[16 * 128];   // q0..7 top, q8..15 bottom: 4 lvls (hg*a,-e) = 32KB
    __shared__ uint4 CP4sh[8 * 128];  // 0..3 top, 4..7 bottom: 8 lvls -cp          = 16KB
    __shared__ uint4 FG4sh[8 * 256];  // 0..3 top, 4..7 bottom: 8 lvls fg           = 32KB

    const int ltid  = threadIdx.x;
    const int tid   = blockIdx.x * 256 + ltid;
    const int field = tid & 3;          // 0=u 1=v 2=t 3=s
    const int col   = tid >> 2;
    const int p     = ltid >> 1;        // pair: (u,v) share akv, (t,s) share akt
    const bool isTS = (field >= 2);

    const float* ak  = isTS ? akt : akv;
    const float* st0 = (field == 0) ? u0 : (field == 1) ? v0 : (field == 2) ? t0 : s0;

    // Coriolis: alpha folded into W at build; rcor = beta/alpha per thread.
    float walpha = 1.0f, rcor = 0.0f;
    {
        float fc   = fcor[col];
        float dtfc = DTF * fc;
        float cff  = dtfc * dtfc;
        float cff1 = 1.0f / (1.0f + GAMMAC * GAMMAC * cff);
        float coefc = 1.0f - GAMMAC * (1.0f - GAMMAC) * cff;
        if (field == 0)      { walpha = cff1 * coefc; rcor =  dtfc / coefc; }
        else if (field == 1) { walpha = cff1 * coefc; rcor = -dtfc / coefc; }
    }

    float bnd0 = 0.f, bnd63 = 0.f;
    if (field == 0)      { bnd0 = -DTF * usb[col]; bnd63 = DTF * uss[col]; }
    else if (field == 1) { bnd0 = -DTF * vsb[col]; bnd63 = DTF * vss[col]; }

    const float* hzc = hz + (size_t)col * NZ;
    const float* akc = ak + (size_t)col * (NZ + 1);
    // uv lanes: fr aliases hzc (L1-hot, value unused) -> no ghost HBM traffic
    const float* fr  = isTS ? (((field == 2) ? tfo : sfo) + (size_t)col * NZ)
                            : hzc;
    float* op = out + ((size_t)field * NCOLS + col) * NZ;

    // ---- build: two mirrored 32-level Thomas folds (r9-proven algebra) ----
    // local j: top k=j (walk down), bottom k=63-j (walk up). Per level:
    // adj = -2dt*ak(link)/(h+hn); g = 1/((h-carry-adj) - carry*chain);
    // publish (h*g*alpha, -carry*g), cp=-(adj*g), fg=rhs*g. Junction links
    // (j=31, both use akc[32]) kept f32 in cpnT/cpnB.
    float cpnT = 0.f, cpnB = 0.f;
    {
        float chT = 0.f, aT = 0.f, hT = hzc[0];
        float chB = 0.f, aB = 0.f, hB = hzc[63];
        uint4 wT = {}, wB = {}, cT = {}, cB = {}, fT = {}, fB = {};
        #pragma unroll
        for (int j = 0; j < 32; ++j) {
            // top level j (k=j)
            float hnT  = hzc[j + 1];
            float adT  = (-2.0f * DTF) * akc[j + 1] / (hT + hnT);
            float gT   = 1.0f / ((hT - aT - adT) - aT * chT);
            float fgT  = isTS ? (DTF * fr[j]) * gT : ((j == 0) ? bnd0 * gT : 0.0f);
            unsigned wvT = packh2(hT * gT * walpha, -aT * gT);
            float cpjT = -(adT * gT);
            // bottom level j (k=63-j)
            float hnB  = hzc[62 - j];
            float adB  = (-2.0f * DTF) * akc[63 - j] / (hB + hnB);
            float gB   = 1.0f / ((hB - aB - adB) - aB * chB);
            float fgB  = isTS ? (DTF * fr[63 - j]) * gB : ((j == 0) ? bnd63 * gB : 0.0f);
            unsigned wvB = packh2(hB * gB * walpha, -aB * gB);
            float cpjB = -(adB * gB);

            // W pack (4 levels / uint4)
            const int j4 = j & 3;
            if (j4 == 0)      { wT.x = wvT; wB.x = wvB; }
            else if (j4 == 1) { wT.y = wvT; wB.y = wvB; }
            else if (j4 == 2) { wT.z = wvT; wB.z = wvB; }
            else {
                wT.w = wvT; wB.w = wvB;
                if ((ltid & 1) == 0) {
                    Wsh[(j >> 2) * 128 + p]       = wT;
                    Wsh[(8 + (j >> 2)) * 128 + p] = wB;
                }
            }
            // CP/FG pack (8 levels / uint4)
            unsigned short cvT = f16bits(cpjT), cvB = f16bits(cpjB);
            unsigned short fvT = f16bits(fgT),  fvB = f16bits(fgB);
            switch (j & 7) {
                case 0: cT.x = cvT; cB.x = cvB; fT.x = fvT; fB.x = fvB; break;
                case 1: cT.x |= ((unsigned)cvT << 16); cB.x |= ((unsigned)cvB << 16);
                        fT.x |= ((unsigned)fvT << 16); fB.x |= ((unsigned)fvB << 16); break;
                case 2: cT.y = cvT; cB.y = cvB; fT.y = fvT; fB.y = fvB; break;
                case 3: cT.y |= ((unsigned)cvT << 16); cB.y |= ((unsigned)cvB << 16);
                        fT.y |= ((unsigned)fvT << 16); fB.y |= ((unsigned)fvB << 16); break;
                case 4: cT.z = cvT; cB.z = cvB; fT.z = fvT; fB.z = fvB; break;
                case 5: cT.z |= ((unsigned)cvT << 16); cB.z |= ((unsigned)cvB << 16);
                        fT.z |= ((unsigned)fvT << 16); fB.z |= ((unsigned)fvB << 16); break;
                case 6: cT.w = cvT; cB.w = cvB; fT.w = fvT; fB.w = fvB; break;
                default:
                    cT.w |= ((unsigned)cvT << 16); cB.w |= ((unsigned)cvB << 16);
                    fT.w |= ((unsigned)fvT << 16); fB.w |= ((unsigned)fvB << 16);
                    FG4sh[(j >> 3) * 256 + ltid]       = fT;
                    FG4sh[(4 + (j >> 3)) * 256 + ltid] = fB;
                    if ((ltid & 1) == 0) {
                        CP4sh[(j >> 3) * 128 + p]       = cT;
                        CP4sh[(4 + (j >> 3)) * 128 + p] = cB;
                    }
                    break;
            }
            if (j == 31) { cpnT = cpjT; cpnB = cpjB; }
            chT = adT * gT; aT = adT; hT = hnT;
            chB = adB * gB; aB = adB; hB = hnB;
            if ((j & 7) == 7) SBAR();
        }
    }
    const float smid = 1.0f / (1.0f - cpnT * cpnB);  // 1/(1 - cp31*eq32)

    // ---- load state (global k order) ----
    float tau[NZ];
    {
        const float4* sp = (const float4*)(st0 + (size_t)col * NZ);
        #pragma unroll
        for (int k4 = 0; k4 < NZ / 4; ++k4) {
            float4 s = sp[k4];
            tau[4*k4+0] = s.x; tau[4*k4+1] = s.y;
            tau[4*k4+2] = s.z; tau[4*k4+3] = s.w;
        }
    }

    // deviation shift for t,s (solve conserves constants exactly)
    float meanadd = 0.0f;
    if (isTS) {
        float ssum = 0.f;
        #pragma unroll
        for (int k = 0; k < NZ; ++k) ssum += tau[k];
        meanadd = ssum * (1.0f / NZ);
        #pragma unroll
        for (int k = 0; k < NZ; ++k) tau[k] -= meanadd;
    }

    __syncthreads();   // coefficients published; LDS read-only from here on

    // ---- 40 time steps: two independent chains per sweep ----
    for (int n = 0; n < NT; ++n) {
        float dpT = 0.f, dpB = 0.f;
        uint4 fTq, fBq;
        #pragma unroll
        for (int q = 0; q < 8; ++q) {
            uint4 wTq = Wsh[q * 128 + p];
            uint4 wBq = Wsh[(8 + q) * 128 + p];
            if ((q & 1) == 0) {
                fTq = FG4sh[(q >> 1) * 256 + ltid];
                fBq = FG4sh[(4 + (q >> 1)) * 256 + ltid];
            }
            #pragma unroll
            for (int i = 0; i < 4; ++i) {
                const int kT = 4*q + i, kB = 63 - kT;
                unsigned wvT = selu4(wTq, i), wvB = selu4(wBq, i);
                const int s = ((q & 1) << 1) | (i >> 1);
                unsigned fwT = selu4(fTq, s), fwB = selu4(fBq, s);
                float fgvT = (i & 1) ? hi16f(fwT) : lo16f(fwT);
                float fgvB = (i & 1) ? hi16f(fwB) : lo16f(fwB);
                float ownT = tau[kT],        ownB = tau[kB];
                float othT = dpp_swap1(ownT), othB = dpp_swap1(ownB);
                float mT = fmaf(rcor, othT, ownT);
                float mB = fmaf(rcor, othB, ownB);
                float tT = fmaf(lo16f(wvT), mT, fgvT);   // off-chain
                float tB = fmaf(lo16f(wvB), mB, fgvB);
                dpT = fmaf(hi16f(wvT), dpT, tT);         // chain T: one fma
                dpB = fmaf(hi16f(wvB), dpB, tB);         // chain B: one fma
                tau[kT] = dpT;
                tau[kB] = dpB;
            }
            if (q & 1) SBAR();
        }
        // junction 2x2 (in-register): x31 = smid*(dpT - cp31*dpB);
        // x32 = dpB - eq32*x31  (cpnT=-cp31, cpnB=-eq32)
        float x31 = smid * fmaf(cpnT, dpB, dpT);
        float x32 = fmaf(cpnB, x31, dpB);
        tau[31] = x31;
        tau[32] = x32;
        // substitution outward: two independent chains
        float xnT = x31, xnB = x32;
        #pragma unroll
        for (int qq = 3; qq >= 0; --qq) {
            uint4 cTq = CP4sh[qq * 128 + p];
            uint4 cBq = CP4sh[(4 + qq) * 128 + p];
            #pragma unroll
            for (int i = 7; i >= 0; --i) {
                const int j = 8*qq + i;
                if (j == 31) continue;        // junction already solved
                unsigned cwT = selu4(cTq, i >> 1), cwB = selu4(cBq, i >> 1);
                float cvT = (i & 1) ? hi16f(cwT) : lo16f(cwT);
                float cvB = (i & 1) ? hi16f(cwB) : lo16f(cwB);
                float xT = fmaf(cvT, xnT, tau[j]);       tau[j] = xT;      xnT = xT;
                float xB = fmaf(cvB, xnB, tau[63 - j]);  tau[63 - j] = xB; xnB = xB;
            }
            if ((qq & 1) == 0) SBAR();
        }
    }

    // ---- store f32 output: out[field][col][k] ----
    #pragma unroll
    for (int k4 = 0; k4 < NZ / 4; ++k4) {
        float4 w;
        w.x = tau[4*k4+0] + meanadd;
        w.y = tau[4*k4+1] + meanadd;
        w.z = tau[4*k4+2] + meanadd;
        w.w = tau[4*k4+3] + meanadd;
        ((float4*)op)[k4] = w;
    }
}

extern "C" void kernel_launch(void* const* d_in, const int* in_sizes, int n_in,
                              void* d_out, int out_size, void* d_ws, size_t ws_size,
                              hipStream_t stream) {
    const float* u0   = (const float*)d_in[0];
    const float* v0   = (const float*)d_in[1];
    const float* t0   = (const float*)d_in[2];
    const float* s0   = (const float*)d_in[3];
    const float* hz   = (const float*)d_in[4];
    const float* akv  = (const float*)d_in[5];
    const float* akt  = (const float*)d_in[6];
    const float* tfo  = (const float*)d_in[7];
    const float* sfo  = (const float*)d_in[8];
    const float* uss  = (const float*)d_in[9];
    const float* vss  = (const float*)d_in[10];
    const float* usb  = (const float*)d_in[11];
    const float* vsb  = (const float*)d_in[12];
    const float* fcor = (const float*)d_in[13];

    scm_kernel<<<dim3((NCOLS * 4) / 256), dim3(256), 0, stream>>>(
        u0, v0, t0, s0, hz, akv, akt, tfo, sfo, uss, vss, usb, vsb, fcor,
        (float*)d_out);
}

// Round 21
// 87.423 us; speedup vs baseline: 2.0729x; 2.0729x over previous
//
#include <hip/hip_runtime.h>
#include <hip/hip_bf16.h>

#define NCOLS 32768
#define NZ 64
#define NT 40
#define DTF 30.0f
#define GAMMAC 0.55f

typedef _Float16 f16;

// Cap the pre-RA scheduler's prefetch window (r4->r5: removed ~200MB of
// scratch-spill HBM traffic caused by hoisted ds_read live ranges).
#define SBAR() __builtin_amdgcn_sched_barrier(0)

// swap lanes (0,1) and (2,3) within each quad: u<->v, t<->s
__device__ __forceinline__ float dpp_swap1(float x) {
    return __int_as_float(__builtin_amdgcn_mov_dpp(__float_as_int(x), 0xB1, 0xF, 0xF, true));
}
__device__ __forceinline__ unsigned int packh2(float a, float b) {
    union { f16 h[2]; unsigned int u; } v;
    v.h[0] = (f16)a; v.h[1] = (f16)b; return v.u;
}
__device__ __forceinline__ unsigned short f16bits(float a) {
    union { f16 h; unsigned short u; } v; v.h = (f16)a; return v.u;
}
__device__ __forceinline__ float lo16f(unsigned int x) {
    union { unsigned int u; f16 h[2]; } v; v.u = x; return (float)v.h[0];
}
__device__ __forceinline__ float hi16f(unsigned int x) {
    union { unsigned int u; f16 h[2]; } v; v.u = x; return (float)v.h[1];
}

// FINAL (= r13, the measured optimum: 87.4us, 88 VGPR, zero spill).
// Session findings baked in:
//  - one thread per (col,field); tid&3 interleave; u<->v via free dpp quad
//    swap; alpha folded into stored hg (rcor = beta/alpha, 0 for t,s).
//  - all time-invariant Thomas coefficients f16x2-packed in LDS, read b128:
//    16 W + 8 FG + 8 CP = 32 ds ops/step. 80KB LDS.
//  - t,s evolve deviations from the column mean (conserved-mode guard for
//    f16 coefficient rounding); absmax 0.25 vs 0.705 threshold.
//  - envelope {256 thr, 80KB LDS, lb(256,2)} is the allocator's proven
//    88-VGPR-grant regime; every >88-demand or small-LDS design spilled
//    (r2,r3,r6,r9,r10,r12,r20), every extra-thread design lost (r19).
// Composed floor: 51us LDS hot loop + ~18us prologue I/O + ~8us epilogue
// ~= 77us vs 87 measured -> ~90% of structural floor.
__global__ __launch_bounds__(256, 2) void scm_kernel(
    const float* __restrict__ u0, const float* __restrict__ v0,
    const float* __restrict__ t0, const float* __restrict__ s0,
    const float* __restrict__ hz, const float* __restrict__ akv,
    const float* __restrict__ akt, const float* __restrict__ tfo,
    const float* __restrict__ sfo, const float* __restrict__ uss,
    const float* __restrict__ vss, const float* __restrict__ usb,
    const float* __restrict__ vsb, const float* __restrict__ fcor,
    float* __restrict__ out)
{
    __shared__ uint4 Wsh[16 * 128];   // [k4][pair] 4 levels (hg*a,-e) = 32KB
    __shared__ uint4 CP4sh[8 * 128];  // [k8][pair] 8 levels -cp       = 16KB
    __shared__ uint4 FG4sh[8 * 256];  // [k8][thread] 8 levels fg      = 32KB

    const int ltid  = threadIdx.x;
    const int tid   = blockIdx.x * 256 + ltid;
    const int field = tid & 3;          // 0=u 1=v 2=t 3=s
    const int col   = tid >> 2;
    const int p     = ltid >> 1;        // pair: (u,v) share akv, (t,s) share akt

    const float* ak  = (field < 2) ? akv : akt;
    const float* st0 = (field == 0) ? u0 : (field == 1) ? v0 : (field == 2) ? t0 : s0;

    // Coriolis: alpha folded into W at build; rcor = beta/alpha per thread.
    float walpha = 1.0f, rcor = 0.0f;
    {
        float fc   = fcor[col];
        float dtfc = DTF * fc;
        float cff  = dtfc * dtfc;
        float cff1 = 1.0f / (1.0f + GAMMAC * GAMMAC * cff);
        float coefc = 1.0f - GAMMAC * (1.0f - GAMMAC) * cff;
        if (field == 0)      { walpha = cff1 * coefc; rcor =  dtfc / coefc; }
        else if (field == 1) { walpha = cff1 * coefc; rcor = -dtfc / coefc; }
    }

    float bnd0 = 0.f, bnd63 = 0.f;
    if (field == 0)      { bnd0 = -DTF * usb[col]; bnd63 = DTF * uss[col]; }
    else if (field == 1) { bnd0 = -DTF * vsb[col]; bnd63 = DTF * vss[col]; }

    const float* hzc = hz + (size_t)col * NZ;
    const float* akc = ak + (size_t)col * (NZ + 1);
    // uv lanes: fr points at hzc (cheap L1 hits) instead of ghost-reading
    // tfo/sfo through the per-lane select. Value unused for uv.
    const float* fr  = (field >= 2) ? (((field == 2) ? tfo : sfo) + (size_t)col * NZ)
                                    : hzc;

    // ---- build folded Thomas coefficients, streamed, 4/8-level packed ----
    // a[k] = -2dt*ak[k]/(hz[k-1]+hz[k]); c[k]=a[k+1]; b[k]=hz[k]-a[k]-c[k]
    // g=1/(b-a*cp_prev); publish hg'=hz*g*alpha, e=a*g, cp=c*g, fg=rhs*g (f16)
    {
        float cpprev = 0.f, aik = 0.f, hk = hzc[0];
        uint4 wacc = {}; uint4 c8 = {}, f8 = {};
        #pragma unroll
        for (int k = 0; k < NZ; ++k) {
            float hk1 = 0.f, aik1 = 0.f;
            float frv = fr[k];
            if (k < NZ - 1) {
                hk1  = hzc[k + 1];
                aik1 = (-2.0f * DTF) * akc[k + 1] / (hk + hk1);
            }
            float bk    = hk - aik - aik1;
            float denom = bk - aik * cpprev;
            float g     = 1.0f / denom;
            float cpk   = aik1 * g;
            float fgk;
            if (field >= 2) fgk = (DTF * frv) * g;
            else            fgk = (k == 0 ? bnd0 : (k == NZ - 1 ? bnd63 : 0.0f)) * g;
            unsigned int   wv = packh2(hk * g * walpha, -aik * g);
            unsigned short cv = f16bits(-cpk);
            unsigned short fv = f16bits(fgk);
            switch (k & 7) {
                case 0: wacc.x = wv; c8.x = cv; f8.x = fv; break;
                case 1: wacc.y = wv; c8.x |= ((unsigned)cv << 16);
                        f8.x |= ((unsigned)fv << 16); break;
                case 2: wacc.z = wv; c8.y = cv; f8.y = fv; break;
                case 3: wacc.w = wv; c8.y |= ((unsigned)cv << 16);
                        f8.y |= ((unsigned)fv << 16);
                        if ((ltid & 1) == 0) Wsh[(k >> 2) * 128 + p] = wacc;
                        break;
                case 4: wacc.x = wv; c8.z = cv; f8.z = fv; break;
                case 5: wacc.y = wv; c8.z |= ((unsigned)cv << 16);
                        f8.z |= ((unsigned)fv << 16); break;
                case 6: wacc.z = wv; c8.w = cv; f8.w = fv; break;
                default:
                    wacc.w = wv; c8.w |= ((unsigned)cv << 16);
                    f8.w |= ((unsigned)fv << 16);
                    FG4sh[(k >> 3) * 256 + ltid] = f8;
                    if ((ltid & 1) == 0) {
                        Wsh[(k >> 2) * 128 + p]   = wacc;
                        CP4sh[(k >> 3) * 128 + p] = c8;
                    }
                    break;
            }
            cpprev = cpk; aik = aik1; hk = hk1;
            if ((k & 15) == 15) SBAR();
        }
    }

    // ---- load state ----
    float tau[NZ];
    {
        const float4* sp = (const float4*)(st0 + (size_t)col * NZ);
        #pragma unroll
        for (int k4 = 0; k4 < NZ / 4; ++k4) {
            float4 s = sp[k4];
            tau[4*k4+0] = s.x; tau[4*k4+1] = s.y;
            tau[4*k4+2] = s.z; tau[4*k4+3] = s.w;
        }
    }

    // deviation shift for t,s (solve conserves constants exactly): evolve
    // tau = state - mean, re-add at the end -> f16 coefficient rounding
    // cannot excite the conserved mode.
    float meanadd = 0.0f;
    if (field >= 2) {
        float ssum = 0.f;
        #pragma unroll
        for (int k = 0; k < NZ; ++k) ssum += tau[k];
        meanadd = ssum * (1.0f / NZ);
        #pragma unroll
        for (int k = 0; k < NZ; ++k) tau[k] -= meanadd;
    }

    __syncthreads();   // coefficients published; LDS read-only from here on

    // ---- 40 time steps: tau in regs, coefficients via wide LDS reads ----
    for (int n = 0; n < NT; ++n) {
        float dpprev = 0.f;
        uint4 f8;
        #pragma unroll
        for (int q = 0; q < 16; ++q) {
            uint4 w = Wsh[q * 128 + p];
            if ((q & 1) == 0) f8 = FG4sh[(q >> 1) * 256 + ltid];
            #pragma unroll
            for (int i = 0; i < 4; ++i) {
                unsigned wv = (i == 0) ? w.x : (i == 1) ? w.y
                            : (i == 2) ? w.z : w.w;
                const int sel = ((q & 1) << 1) | (i >> 1);
                unsigned fgw = (sel == 0) ? f8.x : (sel == 1) ? f8.y
                             : (sel == 2) ? f8.z : f8.w;
                float fgv = (i & 1) ? hi16f(fgw) : lo16f(fgw);
                float own = tau[4*q + i];
                float oth = dpp_swap1(own);             // u<->v partner
                float m   = fmaf(rcor, oth, own);       // ts: rcor=0 -> own
                float dp  = fmaf(lo16f(wv), m, fgv);    // hg'*m + fg
                dp = fmaf(hi16f(wv), dpprev, dp);       // - e*dp_prev
                tau[4*q + i] = dp;
                dpprev = dp;
            }
            if ((q & 3) == 3) SBAR();
        }
        float xn = 0.f;
        uint4 c8;
        #pragma unroll
        for (int q = 15; q >= 0; --q) {
            if ((q & 1) == 1) c8 = CP4sh[(q >> 1) * 128 + p];
            #pragma unroll
            for (int i = 3; i >= 0; --i) {
                const int sel = ((q & 1) << 1) | (i >> 1);
                unsigned cw = (sel == 0) ? c8.x : (sel == 1) ? c8.y
                            : (sel == 2) ? c8.z : c8.w;
                float cv = (i & 1) ? hi16f(cw) : lo16f(cw);
                float x = fmaf(cv, xn, tau[4*q + i]);   // dp - cp*x_next
                tau[4*q + i] = x;
                xn = x;
            }
            if ((q & 3) == 0) SBAR();
        }
    }

    // ---- store f32 output: out[field][col][k] ----
    float* op = out + ((size_t)field * NCOLS + col) * NZ;
    #pragma unroll
    for (int k4 = 0; k4 < NZ / 4; ++k4) {
        float4 w;
        w.x = tau[4*k4+0] + meanadd;
        w.y = tau[4*k4+1] + meanadd;
        w.z = tau[4*k4+2] + meanadd;
        w.w = tau[4*k4+3] + meanadd;
        ((float4*)op)[k4] = w;
    }
}

extern "C" void kernel_launch(void* const* d_in, const int* in_sizes, int n_in,
                              void* d_out, int out_size, void* d_ws, size_t ws_size,
                              hipStream_t stream) {
    const float* u0   = (const float*)d_in[0];
    const float* v0   = (const float*)d_in[1];
    const float* t0   = (const float*)d_in[2];
    const float* s0   = (const float*)d_in[3];
    const float* hz   = (const float*)d_in[4];
    const float* akv  = (const float*)d_in[5];
    const float* akt  = (const float*)d_in[6];
    const float* tfo  = (const float*)d_in[7];
    const float* sfo  = (const float*)d_in[8];
    const float* uss  = (const float*)d_in[9];
    const float* vss  = (const float*)d_in[10];
    const float* usb  = (const float*)d_in[11];
    const float* vsb  = (const float*)d_in[12];
    const float* fcor = (const float*)d_in[13];

    scm_kernel<<<dim3((NCOLS * 4) / 256), dim3(256), 0, stream>>>(
        u0, v0, t0, s0, hz, akv, akt, tfo, sfo, uss, vss, usb, vsb, fcor,
        (float*)d_out);
}